// Round 1
// baseline (416.666 us; speedup 1.0000x reference)
//
#include <hip/hip_runtime.h>
#include <math.h>

// Problem: N=32768, M=4096, H=768 (fp32 in, fp32 out).
// out[0..768)   = fact_      (softmax(fact@(W@ep_^T), axis=0)-weighted row-sum of fact)
// out[768..1536)= elements_p_ (softmax((max_n fact)@W @ ep^T)-weighted row-sum of ep)
// Key reassociation: (fact@W)@ep_^T == fact@(W@ep_^T)  -> matvec, not GEMM.

#define H 768
#define H4 192
#define PSTRIDE 772   // per-block partial: [0]=m, [1]=L, [2..3]=pad, [4..772)=acc[768]
#define ACC_OFF 4

// --- K1: partial column max of fact.  grid 1024 x 192 threads, float4 per thread.
__global__ __launch_bounds__(192) void k_colmax(const float4* __restrict__ x4,
                                                float4* __restrict__ pmax4, int N) {
  const int t = threadIdx.x;
  const int rpb = (N + gridDim.x - 1) / gridDim.x;
  const int n0 = blockIdx.x * rpb;
  const int n1 = min(N, n0 + rpb);
  float4 m = make_float4(-INFINITY, -INFINITY, -INFINITY, -INFINITY);
#pragma unroll 4
  for (int n = n0; n < n1; ++n) {
    float4 x = x4[(size_t)n * H4 + t];
    m.x = fmaxf(m.x, x.x); m.y = fmaxf(m.y, x.y);
    m.z = fmaxf(m.z, x.z); m.w = fmaxf(m.w, x.w);
  }
  pmax4[(size_t)blockIdx.x * H4 + t] = m;
}

// --- K2: reduce partial maxes -> fact_Q[768]; also zero q.  grid 12 x 64.
__global__ __launch_bounds__(64) void k_colreduce(const float* __restrict__ pmax,
                                                  float* __restrict__ fQ,
                                                  float* __restrict__ q, int B) {
  const int c = blockIdx.x * 64 + threadIdx.x;
  float m = -INFINITY;
#pragma unroll 8
  for (int b = 0; b < B; ++b) m = fmaxf(m, pmax[(size_t)b * H + c]);
  fQ[c] = m;
  q[c] = 0.f;
}

// --- K3: q[h] = sum_k fQ[k] * W[k,h], k-chunked, atomicAdd.  grid 24 x 192.
__global__ __launch_bounds__(192) void k_q(const float4* __restrict__ W4,
                                           const float* __restrict__ fQ,
                                           float* __restrict__ q) {
  const int t = threadIdx.x;
  const int k0 = blockIdx.x * 32;
  float4 acc = make_float4(0.f, 0.f, 0.f, 0.f);
#pragma unroll 4
  for (int k = k0; k < k0 + 32; ++k) {
    const float f = fQ[k];
    const float4 w = W4[(size_t)k * H4 + t];
    acc.x = fmaf(f, w.x, acc.x);
    acc.y = fmaf(f, w.y, acc.y);
    acc.z = fmaf(f, w.z, acc.z);
    acc.w = fmaf(f, w.w, acc.w);
  }
  atomicAdd(&q[4 * t + 0], acc.x);
  atomicAdd(&q[4 * t + 1], acc.y);
  atomicAdd(&q[4 * t + 2], acc.z);
  atomicAdd(&q[4 * t + 3], acc.w);
}

// --- K4/K7: online-softmax weighted row-sum pass.
// s_r = dot(X[r,:], wv_); block partial: m_b, L_b = sum exp(s-m_b),
// acc_b = sum exp(s-m_b)*X[r,:].  One wave per row-chunk; row stays in regs.
template <int NW>
__global__ __launch_bounds__(NW * 64) void k_pass(const float4* __restrict__ X4,
                                                  const float* __restrict__ wv_,
                                                  float* __restrict__ part, int R) {
  const int lane = threadIdx.x & 63;
  const int wv = threadIdx.x >> 6;
  const int gw = blockIdx.x * NW + wv;
  const int nw = gridDim.x * NW;
  float4 wr[3];
#pragma unroll
  for (int j = 0; j < 3; ++j) wr[j] = ((const float4*)wv_)[lane + 64 * j];
  const int rpw = (R + nw - 1) / nw;
  const int r0 = gw * rpw;
  const int r1 = min(R, r0 + rpw);
  float mrun = -INFINITY, l = 0.f;
  float4 acc[3];
#pragma unroll
  for (int j = 0; j < 3; ++j) acc[j] = make_float4(0.f, 0.f, 0.f, 0.f);
  for (int r = r0; r < r1; ++r) {
    const float4* row = X4 + (size_t)r * H4;
    float4 x[3];
    float s = 0.f;
#pragma unroll
    for (int j = 0; j < 3; ++j) {
      x[j] = row[lane + 64 * j];
      s = fmaf(x[j].x, wr[j].x, s);
      s = fmaf(x[j].y, wr[j].y, s);
      s = fmaf(x[j].z, wr[j].z, s);
      s = fmaf(x[j].w, wr[j].w, s);
    }
#pragma unroll
    for (int o = 32; o; o >>= 1) s += __shfl_xor(s, o, 64);
    const float mn = fmaxf(mrun, s);
    const float esc = __expf(mrun - mn);  // exp(-inf)=0 on first row
    const float p = __expf(s - mn);
    l = fmaf(l, esc, p);
#pragma unroll
    for (int j = 0; j < 3; ++j) {
      acc[j].x = fmaf(acc[j].x, esc, p * x[j].x);
      acc[j].y = fmaf(acc[j].y, esc, p * x[j].y);
      acc[j].z = fmaf(acc[j].z, esc, p * x[j].z);
      acc[j].w = fmaf(acc[j].w, esc, p * x[j].w);
    }
    mrun = mn;
  }
  __shared__ float sm[NW], sl[NW];
  __shared__ float4 sacc[NW][H4];
  if (lane == 0) { sm[wv] = mrun; sl[wv] = l; }
#pragma unroll
  for (int j = 0; j < 3; ++j) sacc[wv][lane + 64 * j] = acc[j];
  __syncthreads();
  if (wv == 0) {
    float gm = -INFINITY;
#pragma unroll
    for (int w2 = 0; w2 < NW; ++w2) gm = fmaxf(gm, sm[w2]);
    float fa[NW];
    float L = 0.f;
#pragma unroll
    for (int w2 = 0; w2 < NW; ++w2) {
      fa[w2] = (sl[w2] > 0.f) ? __expf(sm[w2] - gm) : 0.f;  // empty-wave guard
      L = fmaf(fa[w2], sl[w2], L);
    }
    float* pb = part + (size_t)blockIdx.x * PSTRIDE;
#pragma unroll
    for (int j = 0; j < 3; ++j) {
      float4 a = make_float4(0.f, 0.f, 0.f, 0.f);
#pragma unroll
      for (int w2 = 0; w2 < NW; ++w2) {
        const float4 t = sacc[w2][lane + 64 * j];
        a.x = fmaf(fa[w2], t.x, a.x);
        a.y = fmaf(fa[w2], t.y, a.y);
        a.z = fmaf(fa[w2], t.z, a.z);
        a.w = fmaf(fa[w2], t.w, a.w);
      }
      *(float4*)(pb + ACC_OFF + 4 * (lane + 64 * j)) = a;
    }
    if (lane == 0) { pb[0] = gm; pb[1] = L; }
  }
}

// --- K5/K8: merge block partials -> normalized weighted sum.  grid 12 x 64.
__global__ __launch_bounds__(64) void k_combine(const float* __restrict__ part, int B,
                                                float* __restrict__ out0,
                                                float* __restrict__ out1) {
  const int lane = threadIdx.x;
  float gm = -INFINITY;
  for (int b = lane; b < B; b += 64) gm = fmaxf(gm, part[(size_t)b * PSTRIDE]);
#pragma unroll
  for (int o = 32; o; o >>= 1) gm = fmaxf(gm, __shfl_xor(gm, o, 64));
  __shared__ float se[512];
  float L = 0.f;
  for (int b = lane; b < B; b += 64) {
    const float m = part[(size_t)b * PSTRIDE];
    const float lb = part[(size_t)b * PSTRIDE + 1];
    const float e = (lb > 0.f) ? __expf(m - gm) : 0.f;
    se[b] = e;
    L = fmaf(e, lb, L);
  }
#pragma unroll
  for (int o = 32; o; o >>= 1) L += __shfl_xor(L, o, 64);
  __syncthreads();
  const int c = blockIdx.x * 64 + lane;
  float a = 0.f;
#pragma unroll 4
  for (int b = 0; b < B; ++b)
    a = fmaf(se[b], part[(size_t)b * PSTRIDE + ACC_OFF + c], a);
  const float r = a / L;
  out0[c] = r;
  if (out1) out1[c] = r;
}

// --- K6: v[i] = dot(W[i,:], ep_).  One wave per output row.  grid 192 x 256.
__global__ __launch_bounds__(256) void k_v(const float4* __restrict__ W4,
                                           const float* __restrict__ ep_,
                                           float* __restrict__ v) {
  const int lane = threadIdx.x & 63;
  const int i = blockIdx.x * 4 + (threadIdx.x >> 6);
  float s = 0.f;
#pragma unroll
  for (int j = 0; j < 3; ++j) {
    const float4 w = W4[(size_t)i * H4 + lane + 64 * j];
    const float4 e = ((const float4*)ep_)[lane + 64 * j];
    s = fmaf(w.x, e.x, s);
    s = fmaf(w.y, e.y, s);
    s = fmaf(w.z, e.z, s);
    s = fmaf(w.w, e.w, s);
  }
#pragma unroll
  for (int o = 32; o; o >>= 1) s += __shfl_xor(s, o, 64);
  if (lane == 0) v[i] = s;
}

extern "C" void kernel_launch(void* const* d_in, const int* in_sizes, int n_in,
                              void* d_out, int out_size, void* d_ws, size_t ws_size,
                              hipStream_t stream) {
  const float* fact = (const float*)d_in[0];  // [N,H]
  const float* ep   = (const float*)d_in[1];  // [M,H]
  const float* W    = (const float*)d_in[2];  // [H,H]
  float* out = (float*)d_out;                 // [0..H)=fact_, [H..2H)=elements_p_
  const int N = in_sizes[0] / H;
  const int M = in_sizes[1] / H;

  const int B1 = 1024;  // colmax partial blocks
  const int BM = 128;   // M-pass blocks (x8 waves)
  const int BN = 512;   // N-pass blocks (x8 waves)

  float* wsf  = (float*)d_ws;
  float* fQ   = wsf;                   // 768
  float* q    = wsf + 768;             // 768
  float* v    = wsf + 1536;            // 768
  float* epws = wsf + 2304;            // 768
  float* pmax = wsf + 3072;            // B1*768
  float* pm   = pmax + (size_t)B1 * H; // BM*772
  float* pn   = pm + (size_t)BM * PSTRIDE;  // BN*772

  k_colmax<<<B1, 192, 0, stream>>>((const float4*)fact, (float4*)pmax, N);
  k_colreduce<<<12, 64, 0, stream>>>(pmax, fQ, q, B1);
  k_q<<<24, 192, 0, stream>>>((const float4*)W, fQ, q);
  k_pass<8><<<BM, 512, 0, stream>>>((const float4*)ep, q, pm, M);
  k_combine<<<12, 64, 0, stream>>>(pm, BM, out + H, epws);
  k_v<<<192, 256, 0, stream>>>((const float4*)W, epws, v);
  k_pass<8><<<BN, 512, 0, stream>>>((const float4*)fact, v, pn, N);
  k_combine<<<12, 64, 0, stream>>>(pn, BN, out, nullptr);
}

// Round 2
// 264.166 us; speedup vs baseline: 1.5773x; 1.5773x over previous
//
#include <hip/hip_runtime.h>
#include <math.h>

// Problem: N=32768, M=4096, H=768 (fp32 in, fp32 out).
// out[0..768)   = fact_      (softmax(fact@(W@ep_^T), axis=0)-weighted row-sum of fact)
// out[768..1536)= elements_p_ (softmax((max_n fact)@W @ ep^T)-weighted row-sum of ep)
// Key reassociation: (fact@W)@ep_^T == fact@(W@ep_^T)  -> matvec, not GEMM.
// HBM floor: ~219 MB (fact x2 + ep + W x2) / 6.3 TB/s ~= 35 us.

#define H 768
#define H4 192
#define PSTRIDE 772   // per-block partial: [0]=m, [1]=L, [2..3]=pad, [4..772)=acc[768]
#define ACC_OFF 4

// --- K1: partial column max of fact.  grid 1024 x 192 threads, float4 per thread.
__global__ __launch_bounds__(192) void k_colmax(const float4* __restrict__ x4,
                                                float4* __restrict__ pmax4, int N) {
  const int t = threadIdx.x;
  const int rpb = (N + gridDim.x - 1) / gridDim.x;
  const int n0 = blockIdx.x * rpb;
  const int n1 = min(N, n0 + rpb);
  float4 m = make_float4(-INFINITY, -INFINITY, -INFINITY, -INFINITY);
#pragma unroll 8
  for (int n = n0; n < n1; ++n) {
    float4 x = x4[(size_t)n * H4 + t];
    m.x = fmaxf(m.x, x.x); m.y = fmaxf(m.y, x.y);
    m.z = fmaxf(m.z, x.z); m.w = fmaxf(m.w, x.w);
  }
  pmax4[(size_t)blockIdx.x * H4 + t] = m;
}

// --- K2: reduce partial maxes -> fact_Q[768]; also zero q.
// grid 12 x 1024 (16 waves): wave w strides the b axis, LDS tree-combine.
// (R1 post-mortem: the 64-thread serial version was 173 us @ 9 GB/s, latency-bound.)
__global__ __launch_bounds__(1024) void k_colreduce(const float* __restrict__ pmax,
                                                    float* __restrict__ fQ,
                                                    float* __restrict__ q, int B) {
  const int lane = threadIdx.x & 63;
  const int wv = threadIdx.x >> 6;  // 0..15
  const int c = blockIdx.x * 64 + lane;
  float m = -INFINITY;
#pragma unroll 4
  for (int b = wv; b < B; b += 16) m = fmaxf(m, pmax[(size_t)b * H + c]);
  __shared__ float s[16][64];
  s[wv][lane] = m;
  __syncthreads();
  if (wv == 0) {
    float mm = m;
#pragma unroll
    for (int w2 = 1; w2 < 16; ++w2) mm = fmaxf(mm, s[w2][lane]);
    fQ[c] = mm;
    q[c] = 0.f;
  }
}

// --- K3: q[h] = sum_k fQ[k] * W[k,h], k-chunked, atomicAdd.  grid 48 x 192.
__global__ __launch_bounds__(192) void k_q(const float4* __restrict__ W4,
                                           const float* __restrict__ fQ,
                                           float* __restrict__ q) {
  const int t = threadIdx.x;
  const int k0 = blockIdx.x * 16;
  float4 acc = make_float4(0.f, 0.f, 0.f, 0.f);
#pragma unroll 4
  for (int k = k0; k < k0 + 16; ++k) {
    const float f = fQ[k];
    const float4 w = W4[(size_t)k * H4 + t];
    acc.x = fmaf(f, w.x, acc.x);
    acc.y = fmaf(f, w.y, acc.y);
    acc.z = fmaf(f, w.z, acc.z);
    acc.w = fmaf(f, w.w, acc.w);
  }
  atomicAdd(&q[4 * t + 0], acc.x);
  atomicAdd(&q[4 * t + 1], acc.y);
  atomicAdd(&q[4 * t + 2], acc.z);
  atomicAdd(&q[4 * t + 3], acc.w);
}

// --- K4/K7: online-softmax weighted row-sum pass.
// s_r = dot(X[r,:], wv_); block partial: m_b, L_b = sum exp(s-m_b),
// acc_b = sum exp(s-m_b)*X[r,:].  One wave per row-chunk; row stays in regs.
template <int NW>
__global__ __launch_bounds__(NW * 64) void k_pass(const float4* __restrict__ X4,
                                                  const float* __restrict__ wv_,
                                                  float* __restrict__ part, int R) {
  const int lane = threadIdx.x & 63;
  const int wv = threadIdx.x >> 6;
  const int gw = blockIdx.x * NW + wv;
  const int nw = gridDim.x * NW;
  float4 wr[3];
#pragma unroll
  for (int j = 0; j < 3; ++j) wr[j] = ((const float4*)wv_)[lane + 64 * j];
  const int rpw = (R + nw - 1) / nw;
  const int r0 = gw * rpw;
  const int r1 = min(R, r0 + rpw);
  float mrun = -INFINITY, l = 0.f;
  float4 acc[3];
#pragma unroll
  for (int j = 0; j < 3; ++j) acc[j] = make_float4(0.f, 0.f, 0.f, 0.f);
  for (int r = r0; r < r1; ++r) {
    const float4* row = X4 + (size_t)r * H4;
    float4 x[3];
    float s = 0.f;
#pragma unroll
    for (int j = 0; j < 3; ++j) {
      x[j] = row[lane + 64 * j];
      s = fmaf(x[j].x, wr[j].x, s);
      s = fmaf(x[j].y, wr[j].y, s);
      s = fmaf(x[j].z, wr[j].z, s);
      s = fmaf(x[j].w, wr[j].w, s);
    }
#pragma unroll
    for (int o = 32; o; o >>= 1) s += __shfl_xor(s, o, 64);
    const float mn = fmaxf(mrun, s);
    const float esc = __expf(mrun - mn);  // exp(-inf)=0 on first row
    const float p = __expf(s - mn);
    l = fmaf(l, esc, p);
#pragma unroll
    for (int j = 0; j < 3; ++j) {
      acc[j].x = fmaf(acc[j].x, esc, p * x[j].x);
      acc[j].y = fmaf(acc[j].y, esc, p * x[j].y);
      acc[j].z = fmaf(acc[j].z, esc, p * x[j].z);
      acc[j].w = fmaf(acc[j].w, esc, p * x[j].w);
    }
    mrun = mn;
  }
  __shared__ float sm[NW], sl[NW];
  __shared__ float4 sacc[NW][H4];
  if (lane == 0) { sm[wv] = mrun; sl[wv] = l; }
#pragma unroll
  for (int j = 0; j < 3; ++j) sacc[wv][lane + 64 * j] = acc[j];
  __syncthreads();
  if (wv == 0) {
    float gm = -INFINITY;
#pragma unroll
    for (int w2 = 0; w2 < NW; ++w2) gm = fmaxf(gm, sm[w2]);
    float fa[NW];
    float L = 0.f;
#pragma unroll
    for (int w2 = 0; w2 < NW; ++w2) {
      fa[w2] = (sl[w2] > 0.f) ? __expf(sm[w2] - gm) : 0.f;  // empty-wave guard
      L = fmaf(fa[w2], sl[w2], L);
    }
    float* pb = part + (size_t)blockIdx.x * PSTRIDE;
#pragma unroll
    for (int j = 0; j < 3; ++j) {
      float4 a = make_float4(0.f, 0.f, 0.f, 0.f);
#pragma unroll
      for (int w2 = 0; w2 < NW; ++w2) {
        const float4 t = sacc[w2][lane + 64 * j];
        a.x = fmaf(fa[w2], t.x, a.x);
        a.y = fmaf(fa[w2], t.y, a.y);
        a.z = fmaf(fa[w2], t.z, a.z);
        a.w = fmaf(fa[w2], t.w, a.w);
      }
      *(float4*)(pb + ACC_OFF + 4 * (lane + 64 * j)) = a;
    }
    if (lane == 0) { pb[0] = gm; pb[1] = L; }
  }
}

// --- K5/K8: merge block partials -> normalized weighted sum.
// grid 12 x 1024 (16 waves), b axis spread across waves (R1 fix: was 64-thread
// serial loop over B -> latency-bound).
__global__ __launch_bounds__(1024) void k_combine(const float* __restrict__ part, int B,
                                                  float* __restrict__ out0,
                                                  float* __restrict__ out1) {
  const int lane = threadIdx.x & 63;
  const int wv = threadIdx.x >> 6;  // 0..15
  __shared__ float sred[16];
  __shared__ float sacc[16][64];
  // global max over block partials (every thread strides b)
  float gm = -INFINITY;
  for (int b = threadIdx.x; b < B; b += 1024) gm = fmaxf(gm, part[(size_t)b * PSTRIDE]);
#pragma unroll
  for (int o = 32; o; o >>= 1) gm = fmaxf(gm, __shfl_xor(gm, o, 64));
  if (lane == 0) sred[wv] = gm;
  __syncthreads();
  gm = sred[0];
#pragma unroll
  for (int w2 = 1; w2 < 16; ++w2) gm = fmaxf(gm, sred[w2]);
  __syncthreads();  // before reusing sred for L partials
  // L partials per wave
  float L = 0.f;
  for (int b = threadIdx.x; b < B; b += 1024) {
    const float m = part[(size_t)b * PSTRIDE];
    const float lb = part[(size_t)b * PSTRIDE + 1];
    L = fmaf((lb > 0.f) ? __expf(m - gm) : 0.f, lb, L);
  }
#pragma unroll
  for (int o = 32; o; o >>= 1) L += __shfl_xor(L, o, 64);
  if (lane == 0) sred[wv] = L;
  // weighted acc: wave w handles b = w, w+16, ...
  const int c = blockIdx.x * 64 + lane;
  float a = 0.f;
  for (int b = wv; b < B; b += 16) {
    const float m = part[(size_t)b * PSTRIDE];
    const float lb = part[(size_t)b * PSTRIDE + 1];
    const float e = (lb > 0.f) ? __expf(m - gm) : 0.f;
    a = fmaf(e, part[(size_t)b * PSTRIDE + ACC_OFF + c], a);
  }
  sacc[wv][lane] = a;
  __syncthreads();
  if (wv == 0) {
    float s = 0.f, Lt = 0.f;
#pragma unroll
    for (int w2 = 0; w2 < 16; ++w2) { s += sacc[w2][lane]; Lt += sred[w2]; }
    const float r = s / Lt;
    out0[c] = r;
    if (out1) out1[c] = r;
  }
}

// --- K6: v[i] = dot(W[i,:], ep_).  One wave per output row.  grid 192 x 256.
__global__ __launch_bounds__(256) void k_v(const float4* __restrict__ W4,
                                           const float* __restrict__ ep_,
                                           float* __restrict__ v) {
  const int lane = threadIdx.x & 63;
  const int i = blockIdx.x * 4 + (threadIdx.x >> 6);
  float s = 0.f;
#pragma unroll
  for (int j = 0; j < 3; ++j) {
    const float4 w = W4[(size_t)i * H4 + lane + 64 * j];
    const float4 e = ((const float4*)ep_)[lane + 64 * j];
    s = fmaf(w.x, e.x, s);
    s = fmaf(w.y, e.y, s);
    s = fmaf(w.z, e.z, s);
    s = fmaf(w.w, e.w, s);
  }
#pragma unroll
  for (int o = 32; o; o >>= 1) s += __shfl_xor(s, o, 64);
  if (lane == 0) v[i] = s;
}

extern "C" void kernel_launch(void* const* d_in, const int* in_sizes, int n_in,
                              void* d_out, int out_size, void* d_ws, size_t ws_size,
                              hipStream_t stream) {
  const float* fact = (const float*)d_in[0];  // [N,H]
  const float* ep   = (const float*)d_in[1];  // [M,H]
  const float* W    = (const float*)d_in[2];  // [H,H]
  float* out = (float*)d_out;                 // [0..H)=fact_, [H..2H)=elements_p_
  const int N = in_sizes[0] / H;
  const int M = in_sizes[1] / H;

  const int B1 = 1024;  // colmax partial blocks
  const int BM = 256;   // M-pass blocks (x8 waves): rpw=2
  const int BN = 1024;  // N-pass blocks (x8 waves): rpw=4

  float* wsf  = (float*)d_ws;
  float* fQ   = wsf;                   // 768
  float* q    = wsf + 768;             // 768
  float* v    = wsf + 1536;            // 768
  float* epws = wsf + 2304;            // 768
  float* pmax = wsf + 3072;            // B1*768
  float* pm   = pmax + (size_t)B1 * H; // BM*772
  float* pn   = pm + (size_t)BM * PSTRIDE;  // BN*772

  k_colmax<<<B1, 192, 0, stream>>>((const float4*)fact, (float4*)pmax, N);
  k_colreduce<<<12, 1024, 0, stream>>>(pmax, fQ, q, B1);
  k_q<<<48, 192, 0, stream>>>((const float4*)W, fQ, q);
  k_pass<8><<<BM, 512, 0, stream>>>((const float4*)ep, q, pm, M);
  k_combine<<<12, 1024, 0, stream>>>(pm, BM, out + H, epws);
  k_v<<<192, 256, 0, stream>>>((const float4*)W, epws, v);
  k_pass<8><<<BN, 512, 0, stream>>>((const float4*)fact, v, pn, N);
  k_combine<<<12, 1024, 0, stream>>>(pn, BN, out, nullptr);
}

// Round 3
// 241.015 us; speedup vs baseline: 1.7288x; 1.0961x over previous
//
#include <hip/hip_runtime.h>
#include <math.h>

// Problem: N=32768, M=4096, H=768 (fp32 in, fp32 out).
// out[0..768)   = fact_       (softmax(fact@(W@ep_^T), axis=0)-weighted row-sum of fact)
// out[768..1536)= elements_p_ (softmax((max_n fact)@W @ ep^T)-weighted row-sum of ep)
// Reassociation: (fact@W)@x^T == fact@(W@x^T) -> matvecs, never a GEMM.
// HBM floor ~219 MB -> ~35 us.  R2 post-mortem: per-kernel work ~55 us but dur 264 us
// -> serial 8-dispatch chain overhead.  R3: 6 graph nodes, last-block fused combines.

#define H 768
#define H4 192
#define PSTRIDE 772   // per-block partial: [0]=m, [1]=L, [2..3]=pad, [4..772)=acc[768]
#define ACC_OFF 4

// --- K1: partial column max of fact.  grid 256 x 192 threads, float4/thread.
__global__ __launch_bounds__(192) void k_colmax(const float4* __restrict__ x4,
                                                float4* __restrict__ pmax4, int N) {
  const int t = threadIdx.x;
  const int rpb = (N + gridDim.x - 1) / gridDim.x;
  const int n0 = blockIdx.x * rpb;
  const int n1 = min(N, n0 + rpb);
  float4 m = make_float4(-INFINITY, -INFINITY, -INFINITY, -INFINITY);
#pragma unroll 8
  for (int n = n0; n < n1; ++n) {
    float4 x = x4[(size_t)n * H4 + t];
    m.x = fmaxf(m.x, x.x); m.y = fmaxf(m.y, x.y);
    m.z = fmaxf(m.z, x.z); m.w = fmaxf(m.w, x.w);
  }
  pmax4[(size_t)blockIdx.x * H4 + t] = m;
}

// --- K2: fused colmax-reduce + q-chunk.  grid 48 x 192.  Block b owns k-range
// [16b,16b+16): reduces those 16 columns of pmax itself (16 KB from L3), then
// q[h] += sum_k fQ[k]*W[k,h] via atomicAdd (q zeroed by the memset node).
__global__ __launch_bounds__(192) void k_q(const float4* __restrict__ W4,
                                           const float* __restrict__ pmax,
                                           float* __restrict__ q, int B) {
  const int tid = threadIdx.x;
  const int k0 = blockIdx.x * 16;
  __shared__ float sA[12][16];
  __shared__ float fQl[16];
  {  // phase A: fQ for our 16 k's
    const int col = tid & 15;
    const int grp = tid >> 4;  // 0..11
    float m = -INFINITY;
    for (int p = grp; p < B; p += 12) m = fmaxf(m, pmax[(size_t)p * H + k0 + col]);
    sA[grp][col] = m;
    __syncthreads();
    if (tid < 16) {
      float mm = sA[0][tid];
#pragma unroll
      for (int g = 1; g < 12; ++g) mm = fmaxf(mm, sA[g][tid]);
      fQl[tid] = mm;
    }
    __syncthreads();
  }
  float4 acc = make_float4(0.f, 0.f, 0.f, 0.f);
#pragma unroll 4
  for (int kk = 0; kk < 16; ++kk) {
    const float f = fQl[kk];
    const float4 w = W4[(size_t)(k0 + kk) * H4 + tid];
    acc.x = fmaf(f, w.x, acc.x);
    acc.y = fmaf(f, w.y, acc.y);
    acc.z = fmaf(f, w.z, acc.z);
    acc.w = fmaf(f, w.w, acc.w);
  }
  atomicAdd(&q[4 * tid + 0], acc.x);
  atomicAdd(&q[4 * tid + 1], acc.y);
  atomicAdd(&q[4 * tid + 2], acc.z);
  atomicAdd(&q[4 * tid + 3], acc.w);
}

// --- K3/K5: online-softmax weighted row-sum pass WITH fused last-block combine
// (rocPRIM-style arrival: partial write -> __threadfence -> atomicAdd; the last
// block to arrive reduces all partials and writes the final normalized vector).
template <int NW>
__global__ __launch_bounds__(NW * 64) void k_pass(const float4* __restrict__ X4,
                                                  const float* __restrict__ wvec,
                                                  float* __restrict__ part, int R,
                                                  unsigned int* __restrict__ cnt,
                                                  float* __restrict__ outA,
                                                  float* __restrict__ outB) {
  const int lane = threadIdx.x & 63;
  const int wv = threadIdx.x >> 6;
  const int NB = gridDim.x;
  __shared__ float sm[NW], sl[NW];
  __shared__ float4 sacc[NW][H4];

  {  // ---- phase 1: per-wave online softmax over this block's rows
    const int gw = blockIdx.x * NW + wv;
    const int nw = NB * NW;
    float4 wr[3];
#pragma unroll
    for (int j = 0; j < 3; ++j) wr[j] = ((const float4*)wvec)[lane + 64 * j];
    const int rpw = (R + nw - 1) / nw;
    const int r0 = gw * rpw;
    const int r1 = min(R, r0 + rpw);
    float mrun = -INFINITY, l = 0.f;
    float4 acc[3];
#pragma unroll
    for (int j = 0; j < 3; ++j) acc[j] = make_float4(0.f, 0.f, 0.f, 0.f);
    for (int r = r0; r < r1; ++r) {
      const float4* row = X4 + (size_t)r * H4;
      float4 x[3];
      float s = 0.f;
#pragma unroll
      for (int j = 0; j < 3; ++j) {
        x[j] = row[lane + 64 * j];
        s = fmaf(x[j].x, wr[j].x, s);
        s = fmaf(x[j].y, wr[j].y, s);
        s = fmaf(x[j].z, wr[j].z, s);
        s = fmaf(x[j].w, wr[j].w, s);
      }
#pragma unroll
      for (int o = 32; o; o >>= 1) s += __shfl_xor(s, o, 64);
      const float mn = fmaxf(mrun, s);
      const float esc = __expf(mrun - mn);  // exp(-inf)=0 on first row
      const float p = __expf(s - mn);
      l = fmaf(l, esc, p);
#pragma unroll
      for (int j = 0; j < 3; ++j) {
        acc[j].x = fmaf(acc[j].x, esc, p * x[j].x);
        acc[j].y = fmaf(acc[j].y, esc, p * x[j].y);
        acc[j].z = fmaf(acc[j].z, esc, p * x[j].z);
        acc[j].w = fmaf(acc[j].w, esc, p * x[j].w);
      }
      mrun = mn;
    }
    if (lane == 0) { sm[wv] = mrun; sl[wv] = l; }
#pragma unroll
    for (int j = 0; j < 3; ++j) sacc[wv][lane + 64 * j] = acc[j];
    __syncthreads();
    if (wv == 0) {  // block-level merge, write partial
      float gm = -INFINITY;
#pragma unroll
      for (int w2 = 0; w2 < NW; ++w2) gm = fmaxf(gm, sm[w2]);
      float fa[NW];
      float L = 0.f;
#pragma unroll
      for (int w2 = 0; w2 < NW; ++w2) {
        fa[w2] = (sl[w2] > 0.f) ? __expf(sm[w2] - gm) : 0.f;
        L = fmaf(fa[w2], sl[w2], L);
      }
      float* pb = part + (size_t)blockIdx.x * PSTRIDE;
#pragma unroll
      for (int j = 0; j < 3; ++j) {
        float4 a = make_float4(0.f, 0.f, 0.f, 0.f);
#pragma unroll
        for (int w2 = 0; w2 < NW; ++w2) {
          const float4 t = sacc[w2][lane + 64 * j];
          a.x = fmaf(fa[w2], t.x, a.x);
          a.y = fmaf(fa[w2], t.y, a.y);
          a.z = fmaf(fa[w2], t.z, a.z);
          a.w = fmaf(fa[w2], t.w, a.w);
        }
        *(float4*)(pb + ACC_OFF + 4 * (lane + 64 * j)) = a;
      }
      if (lane == 0) { pb[0] = gm; pb[1] = L; }
    }
  }

  // ---- arrival: last block to finish does the global combine
  __syncthreads();  // drains vmcnt(0): partial stores complete
  __shared__ unsigned int s_last;
  if (threadIdx.x == 0) {
    __threadfence();
    s_last = atomicAdd(cnt, 1u);
  }
  __syncthreads();
  if (s_last != (unsigned)(NB - 1)) return;
  __threadfence();

  {  // ---- phase 2: combine NB partials (one block, NW waves)
    __shared__ float sred[NW];
    const float* P = part;
    float gm = -INFINITY;
    for (int b = threadIdx.x; b < NB; b += NW * 64) gm = fmaxf(gm, P[(size_t)b * PSTRIDE]);
#pragma unroll
    for (int o = 32; o; o >>= 1) gm = fmaxf(gm, __shfl_xor(gm, o, 64));
    if (lane == 0) sred[wv] = gm;
    __syncthreads();
    gm = sred[0];
#pragma unroll
    for (int w2 = 1; w2 < NW; ++w2) gm = fmaxf(gm, sred[w2]);
    __syncthreads();
    float L = 0.f;
    for (int b = threadIdx.x; b < NB; b += NW * 64) {
      const float m = P[(size_t)b * PSTRIDE];
      const float lb = P[(size_t)b * PSTRIDE + 1];
      L = fmaf((lb > 0.f) ? __expf(m - gm) : 0.f, lb, L);
    }
#pragma unroll
    for (int o = 32; o; o >>= 1) L += __shfl_xor(L, o, 64);
    if (lane == 0) sred[wv] = L;
    // weighted acc: wave wv takes b = wv, wv+NW, ...
    float4 a[3];
#pragma unroll
    for (int j = 0; j < 3; ++j) a[j] = make_float4(0.f, 0.f, 0.f, 0.f);
    for (int b = wv; b < NB; b += NW) {
      const float m = P[(size_t)b * PSTRIDE];
      const float lb = P[(size_t)b * PSTRIDE + 1];
      const float e = (lb > 0.f) ? __expf(m - gm) : 0.f;
      const float4* pa = (const float4*)(P + (size_t)b * PSTRIDE + ACC_OFF);
#pragma unroll
      for (int j = 0; j < 3; ++j) {
        const float4 t = pa[lane + 64 * j];
        a[j].x = fmaf(e, t.x, a[j].x);
        a[j].y = fmaf(e, t.y, a[j].y);
        a[j].z = fmaf(e, t.z, a[j].z);
        a[j].w = fmaf(e, t.w, a[j].w);
      }
    }
#pragma unroll
    for (int j = 0; j < 3; ++j) sacc[wv][lane + 64 * j] = a[j];
    __syncthreads();
    if (threadIdx.x < H4) {
      float4 s = sacc[0][threadIdx.x];
#pragma unroll
      for (int w2 = 1; w2 < NW; ++w2) {
        const float4 t = sacc[w2][threadIdx.x];
        s.x += t.x; s.y += t.y; s.z += t.z; s.w += t.w;
      }
      float Lt = sred[0];
#pragma unroll
      for (int w2 = 1; w2 < NW; ++w2) Lt += sred[w2];
      const float inv = 1.f / Lt;
      const float4 r = make_float4(s.x * inv, s.y * inv, s.z * inv, s.w * inv);
      ((float4*)outA)[threadIdx.x] = r;
      if (outB) ((float4*)outB)[threadIdx.x] = r;
    }
  }
}

// --- K4: v[i] = dot(W[i,:], ep_).  One wave per output row.  grid 192 x 256.
__global__ __launch_bounds__(256) void k_v(const float4* __restrict__ W4,
                                           const float* __restrict__ ep_,
                                           float* __restrict__ v) {
  const int lane = threadIdx.x & 63;
  const int i = blockIdx.x * 4 + (threadIdx.x >> 6);
  float s = 0.f;
#pragma unroll
  for (int j = 0; j < 3; ++j) {
    const float4 w = W4[(size_t)i * H4 + lane + 64 * j];
    const float4 e = ((const float4*)ep_)[lane + 64 * j];
    s = fmaf(w.x, e.x, s);
    s = fmaf(w.y, e.y, s);
    s = fmaf(w.z, e.z, s);
    s = fmaf(w.w, e.w, s);
  }
#pragma unroll
  for (int o = 32; o; o >>= 1) s += __shfl_xor(s, o, 64);
  if (lane == 0) v[i] = s;
}

extern "C" void kernel_launch(void* const* d_in, const int* in_sizes, int n_in,
                              void* d_out, int out_size, void* d_ws, size_t ws_size,
                              hipStream_t stream) {
  const float* fact = (const float*)d_in[0];  // [N,H]
  const float* ep   = (const float*)d_in[1];  // [M,H]
  const float* W    = (const float*)d_in[2];  // [H,H]
  float* out = (float*)d_out;                 // [0..H)=fact_, [H..2H)=elements_p_
  const int N = in_sizes[0] / H;
  const int M = in_sizes[1] / H;

  const int B1 = 256;  // colmax partial blocks (128 rows each)
  const int BM = 128;  // ep-pass blocks (x8 waves): rpw=4
  const int BN = 256;  // fact-pass blocks (x8 waves): rpw=16

  // ws layout (floats). counters+q zeroed by one memset node (3088 B).
  float* wsf  = (float*)d_ws;
  unsigned int* cnt2 = (unsigned int*)d_ws;       // [0]
  unsigned int* cnt3 = (unsigned int*)d_ws + 1;   // [1]
  float* q    = wsf + 4;                          // 768
  float* epws = wsf + 772;                        // 768
  float* v    = wsf + 1540;                       // 768 (+pad to 2308)
  float* pmax = wsf + 2308;                       // B1*768
  float* pm   = pmax + (size_t)B1 * H;            // BM*772
  float* pn   = pm + (size_t)BM * PSTRIDE;        // BN*772

  hipMemsetAsync(d_ws, 0, 3088, stream);  // counters + q
  k_colmax<<<B1, 192, 0, stream>>>((const float4*)fact, (float4*)pmax, N);
  k_q<<<48, 192, 0, stream>>>((const float4*)W, pmax, q, B1);
  k_pass<8><<<BM, 512, 0, stream>>>((const float4*)ep, q, pm, M, cnt2, epws, out + H);
  k_v<<<192, 256, 0, stream>>>((const float4*)W, epws, v);
  k_pass<8><<<BN, 512, 0, stream>>>((const float4*)fact, v, pn, N, cnt3, out, nullptr);
}